// Round 4
// baseline (240.103 us; speedup 1.0000x reference)
//
#include <hip/hip_runtime.h>
#include <math.h>

#define B_  16
#define C_  64
#define HW_ 128
#define E_  5

typedef __bf16  bf16x8 __attribute__((ext_vector_type(8)));
typedef float   f32x4  __attribute__((ext_vector_type(4)));

// ---- ws byte offsets (same footprint as R3; Mode A verified active) ----
// wEffB: [e(5)][g(2)][tap(9)][q(4)][co(64)][j(8)] ushort = 184320 shorts
#define WS_WEFFB   0
#define WS_BIAS    368640      // float[5*64]
#define WS_POOL    369920      // (unused, kept for layout stability)
#define WS_Z       374016      // float[16] (zeroed by route_kernel)
#define WS_EIDX    374080      // int[16]
#define WS_XT      374144      // bf16 x_t [b][g][row][col][32ci] = 33554432 B
#define WS_EXP     33928576    // bf16 exp [b][co][row][col] = 33554432 B
#define WS_NEED_A  67483008ull

static __device__ __forceinline__ unsigned short f2bf(float f) {
    unsigned int u = __float_as_uint(f);
    unsigned int r = (u + 0x7fffu + ((u >> 16) & 1u)) >> 16;  // RNE
    return (unsigned short)r;
}

// ---------------------------------------------------------------------------
// Kernel 1: transpose fp32 NCHW -> bf16 [b][g][row][col][32ci] + per-row pooling
// grid: (b*128 + row) = 2048 blocks, 256 thr
__global__ __launch_bounds__(256) void transpose_pool_kernel(
        const float* __restrict__ x, unsigned short* __restrict__ x_t,
        float* __restrict__ partial) {
    int bid = blockIdx.x;
    int b = bid >> 7, row = bid & 127;
    int t = threadIdx.x;
    int wave = t >> 6, l = t & 63;
    int half = l >> 5;        // which of 2 ci per iter
    int c4 = l & 31;          // float4 column chunk

    // XOR-swizzled: element (col, ci) at T[col*64 + (ci ^ ((col&7)<<3))]
    __shared__ unsigned short T[128 * 64];

    const float* xb = x + (size_t)b * (64 * 16384) + row * 128;

    #pragma unroll
    for (int it = 0; it < 8; it++) {
        int ci = wave * 16 + it * 2 + half;
        float4 v = *(const float4*)(xb + (size_t)ci * 16384 + c4 * 4);
        float p = v.x + v.y + v.z + v.w;
        p += __shfl_down(p, 16, 32);
        p += __shfl_down(p, 8, 32);
        p += __shfl_down(p, 4, 32);
        p += __shfl_down(p, 2, 32);
        p += __shfl_down(p, 1, 32);
        if (c4 == 0) partial[((size_t)b * 128 + row) * 64 + ci] = p;
        int colb = c4 * 4;
        T[(colb + 0) * 64 + (ci ^ (((colb + 0) & 7) << 3))] = f2bf(v.x);
        T[(colb + 1) * 64 + (ci ^ (((colb + 1) & 7) << 3))] = f2bf(v.y);
        T[(colb + 2) * 64 + (ci ^ (((colb + 2) & 7) << 3))] = f2bf(v.z);
        T[(colb + 3) * 64 + (ci ^ (((colb + 3) & 7) << 3))] = f2bf(v.w);
    }
    __syncthreads();

    uint4* dst = (uint4*)x_t;
    #pragma unroll
    for (int k = 0; k < 4; k++) {
        int chunk = t + k * 256;          // 1024 chunks of 16B
        int col = chunk >> 3, c8 = chunk & 7;
        uint4 vv = *(const uint4*)&T[col * 64 + ((c8 * 8) ^ ((col & 7) << 3))];
        int g = c8 >> 2, qq = c8 & 3;
        dst[((size_t)(b * 2 + g) * 16384 + row * 128 + col) * 4 + qq] = vv;
    }
}

// ---------------------------------------------------------------------------
// Kernel 2: reduce row-partials -> pooled (LDS), then noisy top-1 routing; zero Z
// grid: 1 block x 1024 thr
__global__ __launch_bounds__(1024) void route_kernel(
        const float* __restrict__ partial, const float* __restrict__ noise,
        const float* __restrict__ w_gate, const float* __restrict__ b_gate,
        const float* __restrict__ w_noise, const float* __restrict__ b_noise,
        int* __restrict__ expert_idx, float* __restrict__ Z) {
    __shared__ float pl[1024];
    int t = threadIdx.x;
    int b = t >> 6, ci = t & 63;
    float s = 0.f;
    const float* pp = partial + ((size_t)b * 128) * 64 + ci;
    #pragma unroll 4
    for (int r = 0; r < 128; r++) s += pp[r * 64];
    pl[t] = s * (1.0f / 16384.0f);
    __syncthreads();
    if (t < B_) {
        float best = -1e30f;
        int bi = 0;
        for (int e = 0; e < E_; e++) {
            float lg = b_gate[e], nz = b_noise[e];
            for (int c = 0; c < C_; c++) {
                float pv = pl[t * 64 + c];
                lg += pv * w_gate[c * E_ + e];
                nz += pv * w_noise[c * E_ + e];
            }
            float sp = log1pf(expf(nz));
            float v = lg + noise[t * E_ + e] * sp;
            if (v > best) { best = v; bi = e; }
        }
        expert_idx[t] = bi;
        Z[t] = 0.f;
    }
}

// ---------------------------------------------------------------------------
// Kernel 3: build bf16 effective weights in MFMA A-fragment order
// layout: [e][g(2)][tap(9)][q(4)][co(64)][j(8)], ci = g*32 + q*8 + j
__global__ void build_w_kernel(const float* __restrict__ w1, const float* __restrict__ w_cd,
                               const float* __restrict__ w_hd, const float* __restrict__ w_vd,
                               const float* __restrict__ w_ad,
                               const float* __restrict__ b1, const float* __restrict__ b_cd,
                               const float* __restrict__ b_hd, const float* __restrict__ b_vd,
                               const float* __restrict__ b_ad,
                               unsigned short* __restrict__ wEffB, float* __restrict__ biasEff) {
    int gid = blockIdx.x * 256 + threadIdx.x;
    if (gid < E_ * 36864) {
        int e   = gid / 36864;
        int r   = gid % 36864;
        int g   = r / 18432;
        int r2  = r % 18432;
        int tap = r2 / 2048;
        int r3  = r2 % 2048;
        int q   = r3 / 512;
        int r4  = r3 % 512;
        int co  = r4 / 8;
        int j   = r4 % 8;
        int ci = g * 32 + q * 8 + j;
        int base9 = (co * 64 + ci) * 9;
        int base3 = (co * 64 + ci) * 3;
        float v = 0.f;
        if (e == 0) {
            v = w1[base9 + tap];
        } else if (e == 1) {
            if (tap == 4) {
                float s = 0.f;
                #pragma unroll
                for (int k = 0; k < 9; k++) s += w_cd[base9 + k];
                v = w_cd[base9 + 4] - s;
            } else {
                v = w_cd[base9 + tap];
            }
        } else if (e == 2) {
            int m = tap % 3;
            if (m == 0) v = w_hd[base3 + tap / 3];
            else if (m == 2) v = -w_hd[base3 + tap / 3];
        } else if (e == 3) {
            if (tap < 3) v = w_vd[base3 + tap];
            else if (tap >= 6) v = -w_vd[base3 + tap - 6];
        } else {
            const int PERM[9] = {3, 0, 1, 6, 4, 2, 7, 8, 5};
            v = w_ad[base9 + tap] - w_ad[base9 + PERM[tap]];
        }
        wEffB[gid] = f2bf(v);
    } else if (gid < E_ * 36864 + E_ * 64) {
        int jj = gid - E_ * 36864;
        int e = jj / 64, co = jj % 64;
        const float* bs;
        switch (e) {
            case 0: bs = b1; break;
            case 1: bs = b_cd; break;
            case 2: bs = b_hd; break;
            case 3: bs = b_vd; break;
            default: bs = b_ad; break;
        }
        biasEff[jj] = bs[co];
    }
}

// ---------------------------------------------------------------------------
// Kernel 4: MFMA implicit-GEMM conv + exp + store + per-example Z sum
// grid: b(16) x rowgroup(32) x colhalf(2) = 1024 blocks, 256 thr (4 waves)
// A fragments read directly from global (L1/L2-resident); only X staged in LDS.
__global__ __launch_bounds__(256, 4) void conv_mfma_kernel(
        const unsigned short* __restrict__ x_t, const unsigned short* __restrict__ wEffB,
        const float* __restrict__ biasEff, const int* __restrict__ expert_idx,
        unsigned short* __restrict__ expw, float* __restrict__ outf,
        float* __restrict__ Z, int direct_f32) {
    int bid = blockIdx.x;
    int b = bid >> 6;
    int rem = bid & 63;
    int rg = rem >> 1;        // 0..31, out rows rg*4..+3
    int ch = rem & 1;         // 0/1,  out cols ch*64..+63

    int t = threadIdx.x;
    int wave = t >> 6;        // out-row-local 0..3
    int lane = t & 63;
    int ln = lane & 15;
    int q = lane >> 4;

    int e = expert_idx[b];

    __shared__ __align__(16) unsigned short Xs[6 * 4 * 68 * 8];   // 26112 B
    __shared__ float zs[4];

    f32x4 acc[4][4];
    #pragma unroll
    for (int i = 0; i < 4; i++)
        #pragma unroll
        for (int jn = 0; jn < 4; jn++)
            acc[i][jn] = (f32x4){0.f, 0.f, 0.f, 0.f};

    const uint4* xq = (const uint4*)x_t;

    for (int g = 0; g < 2; g++) {
        // --- stage X: 6 rows x 66 cols x 4 q-chunks of 8 ci (dense 64B runs) ---
        size_t base_g = (size_t)(b * 2 + g) * 16384 * 4;   // uint4 units
        for (int j = t; j < 1584; j += 256) {
            int cq = j >> 2;          // xr*66 + col
            int xr = cq / 66;
            int col = cq % 66;
            int qq = j & 3;
            int irow = rg * 4 - 1 + xr;
            int icol = ch * 64 - 1 + col;
            uint4 v = make_uint4(0, 0, 0, 0);
            if ((unsigned)irow < 128u && (unsigned)icol < 128u)
                v = xq[base_g + ((size_t)irow * 128 + icol) * 4 + qq];
            *(uint4*)&Xs[((xr * 4 + qq) * 68 + col) * 8] = v;
        }
        __syncthreads();

        const bf16x8* Ag = (const bf16x8*)(wEffB + (size_t)e * 36864 + g * 18432);
        #pragma unroll
        for (int tap = 0; tap < 9; tap++) {
            int dr = tap / 3, dc = tap % 3;
            bf16x8 af[4], bfr[4];
            #pragma unroll
            for (int mt = 0; mt < 4; mt++)
                af[mt] = Ag[(tap * 4 + q) * 64 + mt * 16 + ln];
            int xr = wave + dr;
            #pragma unroll
            for (int t4 = 0; t4 < 4; t4++)
                bfr[t4] = *(const bf16x8*)&Xs[((xr * 4 + q) * 68 + t4 * 16 + ln + dc) * 8];
            #pragma unroll
            for (int mt = 0; mt < 4; mt++)
                #pragma unroll
                for (int t4 = 0; t4 < 4; t4++)
                    acc[mt][t4] = __builtin_amdgcn_mfma_f32_16x16x32_bf16(
                        af[mt], bfr[t4], acc[mt][t4], 0, 0, 0);
        }
        __syncthreads();
    }

    // --- epilogue: bias + exp + store + Z reduction ---
    int orow = rg * 4 + wave;
    float bsum = 0.f;
    size_t obase = (size_t)b * (64 * 16384);
    #pragma unroll
    for (int mt = 0; mt < 4; mt++) {
        float4 bias4 = *(const float4*)(biasEff + e * 64 + mt * 16 + q * 4);
        const float* bp = (const float*)&bias4;
        #pragma unroll
        for (int r = 0; r < 4; r++) {
            int co = mt * 16 + q * 4 + r;
            size_t cb = obase + (size_t)co * 16384 + (size_t)orow * 128;
            #pragma unroll
            for (int t4 = 0; t4 < 4; t4++) {
                float ev = __expf(acc[mt][t4][r] + bp[r]);
                bsum += ev;
                int ocol = ch * 64 + t4 * 16 + ln;
                if (direct_f32) outf[cb + ocol] = ev;
                else            expw[cb + ocol] = f2bf(ev);
            }
        }
    }
    for (int off = 32; off; off >>= 1) bsum += __shfl_down(bsum, off, 64);
    if (lane == 0) zs[wave] = bsum;
    __syncthreads();
    if (t == 0) atomicAdd(&Z[b], zs[0] + zs[1] + zs[2] + zs[3]);
}

// ---------------------------------------------------------------------------
// Kernel 5a: out = bf16_exp * (1/Z[b]) -> fp32 (Mode A)
__global__ __launch_bounds__(256) void scale_bf16_kernel(
        const unsigned short* __restrict__ expw, const float* __restrict__ Z,
        float* __restrict__ out) {
    int gid = blockIdx.x * 256 + threadIdx.x;     // 2,097,152 threads; 8 elems each
    int b = gid >> 17;                            // 131072 uint4-threads per example
    __shared__ float sinv;
    if (threadIdx.x == 0) sinv = 1.0f / Z[b];
    __syncthreads();
    uint4 r = ((const uint4*)expw)[gid];
    float4 o0, o1;
    o0.x = __uint_as_float(r.x << 16) * sinv;
    o0.y = __uint_as_float(r.x & 0xffff0000u) * sinv;
    o0.z = __uint_as_float(r.y << 16) * sinv;
    o0.w = __uint_as_float(r.y & 0xffff0000u) * sinv;
    o1.x = __uint_as_float(r.z << 16) * sinv;
    o1.y = __uint_as_float(r.z & 0xffff0000u) * sinv;
    o1.z = __uint_as_float(r.w << 16) * sinv;
    o1.w = __uint_as_float(r.w & 0xffff0000u) * sinv;
    ((float4*)out)[gid * 2] = o0;
    ((float4*)out)[gid * 2 + 1] = o1;
}

// Kernel 5b: in-place out *= 1/Z[b] (Mode B fallback)
__global__ __launch_bounds__(256) void scale_inplace_kernel(
        float* __restrict__ out, const float* __restrict__ Z) {
    int gid = blockIdx.x * 256 + threadIdx.x;  // over float4s, 4,194,304 total
    int b = gid >> 18;
    __shared__ float sinv;
    if (threadIdx.x == 0) sinv = 1.0f / Z[b];
    __syncthreads();
    float4 v = ((float4*)out)[gid];
    v.x *= sinv; v.y *= sinv; v.z *= sinv; v.w *= sinv;
    ((float4*)out)[gid] = v;
}

// ---------------------------------------------------------------------------
extern "C" void kernel_launch(void* const* d_in, const int* in_sizes, int n_in,
                              void* d_out, int out_size, void* d_ws, size_t ws_size,
                              hipStream_t stream) {
    const float* x       = (const float*)d_in[0];
    const float* noise   = (const float*)d_in[1];
    const float* w_gate  = (const float*)d_in[2];
    const float* b_gate  = (const float*)d_in[3];
    const float* w_noise = (const float*)d_in[4];
    const float* b_noise = (const float*)d_in[5];
    const float* w1      = (const float*)d_in[6];
    const float* b1      = (const float*)d_in[7];
    const float* w_cd    = (const float*)d_in[8];
    const float* b_cd    = (const float*)d_in[9];
    const float* w_hd    = (const float*)d_in[10];
    const float* b_hd    = (const float*)d_in[11];
    const float* w_vd    = (const float*)d_in[12];
    const float* b_vd    = (const float*)d_in[13];
    const float* w_ad    = (const float*)d_in[14];
    const float* b_ad    = (const float*)d_in[15];

    char* ws = (char*)d_ws;
    unsigned short* wEffB   = (unsigned short*)(ws + WS_WEFFB);
    float*          biasEff = (float*)(ws + WS_BIAS);
    float*          Zbuf    = (float*)(ws + WS_Z);
    int*            eidx    = (int*)(ws + WS_EIDX);
    unsigned short* x_t     = (unsigned short*)(ws + WS_XT);
    unsigned short* expw    = (unsigned short*)(ws + WS_EXP);

    float* out = (float*)d_out;
    // partial row-sums live in the tail of d_out (read by route before conv writes)
    float* partial = out + (16 * 1024 * 1024 - 128 * 1024);

    int mode_a = (ws_size >= WS_NEED_A) ? 1 : 0;

    transpose_pool_kernel<<<B_ * 128, 256, 0, stream>>>(x, x_t, partial);
    route_kernel<<<1, 1024, 0, stream>>>(partial, noise, w_gate, b_gate,
                                         w_noise, b_noise, eidx, Zbuf);
    build_w_kernel<<<(E_ * 36864 + E_ * 64 + 255) / 256, 256, 0, stream>>>(
        w1, w_cd, w_hd, w_vd, w_ad, b1, b_cd, b_hd, b_vd, b_ad, wEffB, biasEff);
    conv_mfma_kernel<<<1024, 256, 0, stream>>>(x_t, wEffB, biasEff, eidx,
                                               expw, out, Zbuf, mode_a ? 0 : 1);
    if (mode_a)
        scale_bf16_kernel<<<8192, 256, 0, stream>>>(expw, Zbuf, out);
    else
        scale_inplace_kernel<<<16384, 256, 0, stream>>>(out, Zbuf);
}